// Round 9
// baseline (480.324 us; speedup 1.0000x reference)
//
#include <hip/hip_runtime.h>
#include <math.h>

#define NBR 4
#define NLAY 3
#define Bk 4
#define Tk 1024
#define DIN 32
#define DMODEL 128
#define DINNER 256
#define DSTATE 16
#define DTRANK 8
#define EMBEDk 64
#define BT (Bk*Tk)          /* 4096 rows per branch */
#define EPSF 1e-7f
#define MAXNF 10.0f
#define LCH 32              /* scan chunk length (halved serial chain) */
#define NCH (Tk/LCH)        /* 32 chunks */
#define UF 8                /* t-loop batch (latency amortization) */
#define NWB 384             /* dt|bc panel rows: 256 dt + 32 bc + 96 pad */

typedef __bf16 bf16x8 __attribute__((ext_vector_type(8)));
typedef float  f32x4  __attribute__((ext_vector_type(4)));
typedef unsigned short u16x8 __attribute__((ext_vector_type(8)));
typedef unsigned short u16x4 __attribute__((ext_vector_type(4)));

__device__ __forceinline__ float siluf(float x){ return x / (1.f + __expf(-x)); }
__device__ __forceinline__ float softplusf(float x){ return (x > 20.f) ? x : log1pf(__expf(x)); }
__device__ __forceinline__ unsigned short f2b(float x){
    union { float f; unsigned u; } v; v.f = x;
    unsigned r = v.u + 0x7FFF + ((v.u >> 16) & 1);
    return (unsigned short)(r >> 16);
}
__device__ __forceinline__ float b2f(unsigned short u){
    union { unsigned u; float f; } v; v.u = ((unsigned)u) << 16; return v.f;
}

// async global->LDS, 16 B per lane; LDS dest = wave-uniform base + lane*16
__device__ __forceinline__ void gll16(const void* g, void* l){
    __builtin_amdgcn_global_load_lds(
        (const __attribute__((address_space(1))) unsigned int*)g,
        (__attribute__((address_space(3))) unsigned int*)l,
        16, 0, 0);
}

// 8 powers for the s-split: dA[k] = q^(s0+k+1), s0 = sh*8.  Branchless.
__device__ __forceinline__ void dA_pow8(float q, int sh, float* dA){
    const float q2 = q * q, q4 = q2 * q2, q8 = q4 * q4;
    const float f = sh ? q8 : 1.0f;
    dA[0] = q * f;       dA[1] = q2 * f;
    dA[2] = q2 * q * f;  dA[3] = q4 * f;
    dA[4] = q4 * q * f;  dA[5] = q4 * q2 * f;
    dA[6] = q4 * q2 * q * f; dA[7] = q8 * f;
}

// ---------------------------------------------------------------------------
// bf16 MFMA GEMM, 64x128 tile (two 64-col subtiles per staged A-tile).
// A bf16 [M][K]; B TRANSPOSED bf16 [N][K].  4 waves, 256 thr, 24 KB LDS.
// MODE 0 (xz):  col<256 -> Cu0 bf16 (xp); col>=256 -> Cu1 bf16 silu (z)
// MODE 3 (dtbc): col<256 -> Cu0 bf16 softplus(v+bias) (dt); 256..287 -> Cf (bc)
// ---------------------------------------------------------------------------
template<int MODE>
__global__ __launch_bounds__(256) void bgemm_k(
    const unsigned short* __restrict__ Ab, long aBr, int K,
    const unsigned short* __restrict__ Bt, long bBr,
    unsigned short* __restrict__ Cu0, long cu0Br,
    unsigned short* __restrict__ Cu1, long cu1Br,
    float* __restrict__ Cf, long cfBr,
    const float* __restrict__ bias, long biasBr)
{
    const int br = blockIdx.z;
    Ab += (long)br * aBr;
    Bt += (long)br * bBr;
    Cu0 += (long)br * cu0Br;
    if (MODE == 0) Cu1 += (long)br * cu1Br;
    if (MODE == 3) { Cf += (long)br * cfBr; bias += (long)br * biasBr; }
    const int m0 = blockIdx.x * 64, n0 = blockIdx.y * 128;
    __shared__ __align__(16) unsigned short As[8 * 64 * 8];    // 8 KB  [kch][m][8]
    __shared__ __align__(16) unsigned short Bs[8 * 128 * 8];   // 16 KB [kch][n][8]
    const int tid = threadIdx.x;
    const int lane = tid & 63, w = tid >> 6;
    const int wm = w >> 1, wn = w & 1;
    const int quad = lane >> 4, l15 = lane & 15;
    f32x4 acc[2][4];
    #pragma unroll
    for (int nt = 0; nt < 2; ++nt)
        #pragma unroll
        for (int e = 0; e < 4; ++e) { f32x4 zz = {0,0,0,0}; acc[nt][e] = zz; }
    for (int kc = 0; kc < K; kc += 64) {
        #pragma unroll
        for (int it = 0; it < 2; ++it) {
            const int kch = w + it * 4;   // wave-uniform
            gll16(Ab + (long)(m0 + lane) * K + kc + kch * 8, &As[(kch * 64) * 8]);
        }
        #pragma unroll
        for (int it = 0; it < 4; ++it) {
            const int ub = w * 256 + it * 64;   // wave-uniform
            const int u = ub + lane;
            const int kch = u >> 7, nrow = u & 127;
            gll16(Bt + (long)(n0 + nrow) * K + kc + kch * 8, &Bs[ub * 8]);
        }
        __syncthreads();
        #pragma unroll
        for (int k0 = 0; k0 < 64; k0 += 32) {
            const int kch = (k0 >> 3) + quad;
            bf16x8 a0 = *(const bf16x8*)&As[(kch * 64 + wm * 32 +      l15) * 8];
            bf16x8 a1 = *(const bf16x8*)&As[(kch * 64 + wm * 32 + 16 + l15) * 8];
            #pragma unroll
            for (int nt = 0; nt < 2; ++nt) {
                bf16x8 b0 = *(const bf16x8*)&Bs[(kch * 128 + nt * 64 + wn * 32 +      l15) * 8];
                bf16x8 b1 = *(const bf16x8*)&Bs[(kch * 128 + nt * 64 + wn * 32 + 16 + l15) * 8];
                acc[nt][0] = __builtin_amdgcn_mfma_f32_16x16x32_bf16(a0, b0, acc[nt][0], 0, 0, 0);
                acc[nt][1] = __builtin_amdgcn_mfma_f32_16x16x32_bf16(a0, b1, acc[nt][1], 0, 0, 0);
                acc[nt][2] = __builtin_amdgcn_mfma_f32_16x16x32_bf16(a1, b0, acc[nt][2], 0, 0, 0);
                acc[nt][3] = __builtin_amdgcn_mfma_f32_16x16x32_bf16(a1, b1, acc[nt][3], 0, 0, 0);
            }
        }
        __syncthreads();
    }
    #pragma unroll
    for (int nt = 0; nt < 2; ++nt) {
        #pragma unroll
        for (int e = 0; e < 4; ++e) {
            const f32x4 a = acc[nt][e];
            const int msub = (e >> 1) * 16, nsub = (e & 1) * 16;
            const int col = n0 + nt * 64 + wn * 32 + nsub + l15;
            #pragma unroll
            for (int r = 0; r < 4; ++r) {
                const int row = m0 + wm * 32 + msub + quad * 4 + r;
                const float v = a[r];
                if (MODE == 0) {
                    if (col < 256) Cu0[(long)row * 256 + col] = f2b(v);
                    else           Cu1[(long)row * 256 + (col - 256)] = f2b(siluf(v));
                } else {
                    if (col < 256)      Cu0[(long)row * 256 + col] = f2b(softplusf(v + bias[col]));
                    else if (col < 288) Cf[(long)row * 32 + (col - 256)] = v;
                }
            }
        }
    }
}

// ---------------------------------------------------------------------------
// Depthwise causal conv (4 taps) + bias + silu: bf16 in -> bf16 out.
// 8 channels / thread, u16x8 loads; 2048 blocks (high TLP).
// ---------------------------------------------------------------------------
__global__ __launch_bounds__(256) void conv_k(
    const unsigned short* __restrict__ xp, const float* __restrict__ cw,
    const float* __restrict__ cb, unsigned short* __restrict__ xcb, int layer)
{
    const int br = blockIdx.y;
    const long base = (long)br * BT * DINNER;
    const long idx8 = ((long)blockIdx.x * 256 + threadIdx.x) * 8;
    const int d0 = (int)(idx8 & (DINNER - 1));
    const long row = idx8 >> 8;
    const int t = (int)(row & (Tk - 1));
    const float* cwp = cw + ((long)(br * NLAY + layer) * DINNER + d0) * 4;
    const float* cbp = cb + (long)(br * NLAY + layer) * DINNER + d0;
    u16x8 in[4];
    #pragma unroll
    for (int k = 0; k < 4; ++k) {
        const int tt = t + k - 3;
        if (tt >= 0) {
            in[k] = *(const u16x8*)(xp + base + idx8 + (long)(k - 3) * DINNER);
        } else {
            #pragma unroll
            for (int j = 0; j < 8; ++j) in[k][j] = 0;
        }
    }
    u16x8 o;
    #pragma unroll
    for (int j = 0; j < 8; ++j) {
        float acc = cbp[j];
        #pragma unroll
        for (int k = 0; k < 4; ++k)
            acc = fmaf(b2f(in[k][j]), cwp[j * 4 + k], acc);
        o[j] = f2b(siluf(acc));
    }
    *(u16x8*)(xcb + base + idx8) = o;
}

// ---------------------------------------------------------------------------
// Weight prep GEMM.
//  z<8: WfT[z] = bf16((Wout_p @ Win_{p+1})^T).  z==8: Weq = [Wip;bip]@Win_0.
//  z==9: Wcomb = Wout_2 @ Wop.  z in 10..21: wcombT panel for bl=z-10.
// ---------------------------------------------------------------------------
__global__ __launch_bounds__(256) void sgemmWT_k(
    const float* __restrict__ Wout, const float* __restrict__ Win,
    const float* __restrict__ Wip, const float* __restrict__ bip,
    const float* __restrict__ Wop,
    const float* __restrict__ Wx, const float* __restrict__ Wdt,
    unsigned short* __restrict__ WfT, float* __restrict__ Weq,
    float* __restrict__ Wcomb, unsigned short* __restrict__ WcT)
{
    const int z = blockIdx.z;
    const int tid = threadIdx.x;
    const int tx = tid & 15, ty = tid >> 4;
    __shared__ float As_[32][68];
    __shared__ float Bs_[32][68];
    float acc[4][4] = {};
    if (z < 8) {
        const int p = z >> 2, br = z & 3;
        const float* A  = Wout + (long)(br * NLAY + p) * DINNER * DMODEL;
        const float* Bw = Win  + (long)(br * NLAY + p + 1) * DMODEL * 512;
        const int m0 = blockIdx.x * 64, n0 = blockIdx.y * 64;
        for (int kc = 0; kc < DMODEL; kc += 32) {
            #pragma unroll
            for (int it = 0; it < 2; ++it) {
                int id = tid + it * 256;
                int r = id >> 3, c4 = (id & 7) << 2;
                float4 v = *(const float4*)(A + (long)(m0 + r) * DMODEL + kc + c4);
                As_[c4+0][r] = v.x; As_[c4+1][r] = v.y; As_[c4+2][r] = v.z; As_[c4+3][r] = v.w;
                int rb = id >> 4, cb = (id & 15) << 2;
                *(float4*)&Bs_[rb][cb] = *(const float4*)(Bw + (long)(kc + rb) * 512 + n0 + cb);
            }
            __syncthreads();
            #pragma unroll
            for (int kk = 0; kk < 32; ++kk) {
                float4 a4 = *(const float4*)&As_[kk][ty << 2];
                float4 b4 = *(const float4*)&Bs_[kk][tx << 2];
                float av[4] = {a4.x, a4.y, a4.z, a4.w};
                float bv[4] = {b4.x, b4.y, b4.z, b4.w};
                #pragma unroll
                for (int i = 0; i < 4; ++i)
                    #pragma unroll
                    for (int j = 0; j < 4; ++j)
                        acc[i][j] = fmaf(av[i], bv[j], acc[i][j]);
            }
            __syncthreads();
        }
        unsigned short* o = WfT + (long)z * 512 * 256;
        const int row0 = m0 + (ty << 2), col = n0 + (tx << 2);
        #pragma unroll
        for (int j = 0; j < 4; ++j) {
            u16x4 v;
            #pragma unroll
            for (int i = 0; i < 4; ++i) v[i] = f2b(acc[i][j]);
            *(u16x4*)(o + (long)(col + j) * 256 + row0) = v;
        }
    } else if (z == 8) {
        const int br = blockIdx.x;
        const float* A  = Wip + (long)br * DIN * DMODEL;
        const float* bp = bip + (long)br * DMODEL;
        const float* Bw = Win + (long)br * NLAY * DMODEL * 512;
        const int n0 = blockIdx.y * 64;
        for (int kc = 0; kc < DMODEL; kc += 32) {
            #pragma unroll
            for (int it = 0; it < 2; ++it) {
                int id = tid + it * 256;
                int r = id >> 3, c4 = (id & 7) << 2;
                float4 v;
                if (r < 32)       v = *(const float4*)(A + (long)r * DMODEL + kc + c4);
                else if (r == 32) v = *(const float4*)(bp + kc + c4);
                else              { v.x = 0.f; v.y = 0.f; v.z = 0.f; v.w = 0.f; }
                As_[c4+0][r] = v.x; As_[c4+1][r] = v.y; As_[c4+2][r] = v.z; As_[c4+3][r] = v.w;
                int rb = id >> 4, cb = (id & 15) << 2;
                *(float4*)&Bs_[rb][cb] = *(const float4*)(Bw + (long)(kc + rb) * 512 + n0 + cb);
            }
            __syncthreads();
            #pragma unroll
            for (int kk = 0; kk < 32; ++kk) {
                float4 a4 = *(const float4*)&As_[kk][ty << 2];
                float4 b4 = *(const float4*)&Bs_[kk][tx << 2];
                float av[4] = {a4.x, a4.y, a4.z, a4.w};
                float bv[4] = {b4.x, b4.y, b4.z, b4.w};
                #pragma unroll
                for (int i = 0; i < 4; ++i)
                    #pragma unroll
                    for (int j = 0; j < 4; ++j)
                        acc[i][j] = fmaf(av[i], bv[j], acc[i][j]);
            }
            __syncthreads();
        }
        float* C = Weq + (long)br * 33 * 512;
        const int col = n0 + (tx << 2);
        #pragma unroll
        for (int i = 0; i < 4; ++i) {
            const int row = (ty << 2) + i;
            if (row < 33) {
                float4 v4; v4.x = acc[i][0]; v4.y = acc[i][1]; v4.z = acc[i][2]; v4.w = acc[i][3];
                *(float4*)(C + (long)row * 512 + col) = v4;
            }
        }
    } else if (z == 9) {
        if (blockIdx.y >= 4) return;
        const int br = blockIdx.y;
        const float* A  = Wout + (long)(br * NLAY + 2) * DINNER * DMODEL;
        const float* Bw = Wop  + (long)br * DMODEL * EMBEDk;
        const int m0 = blockIdx.x * 64;
        for (int kc = 0; kc < DMODEL; kc += 32) {
            #pragma unroll
            for (int it = 0; it < 2; ++it) {
                int id = tid + it * 256;
                int r = id >> 3, c4 = (id & 7) << 2;
                float4 v = *(const float4*)(A + (long)(m0 + r) * DMODEL + kc + c4);
                As_[c4+0][r] = v.x; As_[c4+1][r] = v.y; As_[c4+2][r] = v.z; As_[c4+3][r] = v.w;
                int rb = id >> 4, cb = (id & 15) << 2;
                if (cb < 64)
                    *(float4*)&Bs_[rb][cb] = *(const float4*)(Bw + (long)(kc + rb) * EMBEDk + cb);
            }
            __syncthreads();
            #pragma unroll
            for (int kk = 0; kk < 32; ++kk) {
                float4 a4 = *(const float4*)&As_[kk][ty << 2];
                float4 b4 = *(const float4*)&Bs_[kk][tx << 2];
                float av[4] = {a4.x, a4.y, a4.z, a4.w};
                float bv[4] = {b4.x, b4.y, b4.z, b4.w};
                #pragma unroll
                for (int i = 0; i < 4; ++i)
                    #pragma unroll
                    for (int j = 0; j < 4; ++j)
                        acc[i][j] = fmaf(av[i], bv[j], acc[i][j]);
            }
            __syncthreads();
        }
        float* C = Wcomb + (long)br * DINNER * EMBEDk;
        const int col = tx << 2;
        #pragma unroll
        for (int i = 0; i < 4; ++i) {
            const int row = m0 + (ty << 2) + i;
            float4 v4; v4.x = acc[i][0]; v4.y = acc[i][1]; v4.z = acc[i][2]; v4.w = acc[i][3];
            *(float4*)(C + (long)row * EMBEDk + col) = v4;
        }
    } else {   // z in 10..21: wcombT panel for bl = z-10, 12 rows/block
        const int bl = z - 10;
        const int base = (blockIdx.x * 8 + blockIdx.y) * 12;
        const float* WxP = Wx + (long)bl * DINNER * 40;
        const float* WdtP = Wdt + (long)bl * DTRANK * DINNER;
        unsigned short* o = WcT + (long)bl * NWB * DINNER;
        #pragma unroll
        for (int i = 0; i < 12; ++i) {
            const int n = base + i;
            float v;
            if (n < 256) {
                float s = 0.f;
                #pragma unroll
                for (int r = 0; r < 8; ++r) s = fmaf(WxP[tid * 40 + r], WdtP[r * DINNER + n], s);
                v = s;
            } else if (n < 288) {
                v = WxP[tid * 40 + 8 + (n - 256)];
            } else {
                v = 0.f;
            }
            o[(long)n * DINNER + tid] = f2b(v);
        }
    }
}

// ---------------------------------------------------------------------------
// Layer-0 xz: fp32 GEMM x @ Weq + beq (K=32).  col<256 -> xp bf16; else z bf16.
// ---------------------------------------------------------------------------
__global__ __launch_bounds__(256) void xgemm0_k(
    const float* __restrict__ A0, const float* __restrict__ A1,
    const float* __restrict__ A2, const float* __restrict__ A3,
    const float* __restrict__ Weq,
    unsigned short* __restrict__ zb, unsigned short* __restrict__ xpb)
{
    const int br = blockIdx.z;
    const float* A = (br == 1) ? A1 : (br == 2) ? A2 : (br == 3) ? A3 : A0;
    const float* W = Weq + (long)br * 33 * 512;
    unsigned short* Cz = zb + (long)br * BT * DINNER;
    unsigned short* Cb = xpb + (long)br * BT * DINNER;
    const int m0 = blockIdx.x * 64, n0 = blockIdx.y * 64;
    __shared__ float As_[32][68];
    __shared__ float Bs_[32][68];
    const int tid = threadIdx.x;
    const int tx = tid & 15, ty = tid >> 4;
    float acc[4][4] = {};
    {
        #pragma unroll
        for (int it = 0; it < 2; ++it) {
            int id = tid + it * 256;
            int r = id >> 3, c4 = (id & 7) << 2;
            float4 v = *(const float4*)(A + (long)(m0 + r) * DIN + c4);
            As_[c4+0][r] = v.x; As_[c4+1][r] = v.y; As_[c4+2][r] = v.z; As_[c4+3][r] = v.w;
            int rb = id >> 4, cb = (id & 15) << 2;
            *(float4*)&Bs_[rb][cb] = *(const float4*)(W + (long)rb * 512 + n0 + cb);
        }
        __syncthreads();
        #pragma unroll
        for (int kk = 0; kk < 32; ++kk) {
            float4 a4 = *(const float4*)&As_[kk][ty << 2];
            float4 b4 = *(const float4*)&Bs_[kk][tx << 2];
            float av[4] = {a4.x, a4.y, a4.z, a4.w};
            float bv[4] = {b4.x, b4.y, b4.z, b4.w};
            #pragma unroll
            for (int i = 0; i < 4; ++i)
                #pragma unroll
                for (int j = 0; j < 4; ++j)
                    acc[i][j] = fmaf(av[i], bv[j], acc[i][j]);
        }
    }
    const int col = n0 + (tx << 2);
    float be[4];
    #pragma unroll
    for (int j = 0; j < 4; ++j) be[j] = W[32 * 512 + col + j];
    #pragma unroll
    for (int i = 0; i < 4; ++i) {
        const int row = m0 + (ty << 2) + i;
        #pragma unroll
        for (int j = 0; j < 4; ++j) {
            const float v = acc[i][j] + be[j];
            if (n0 < 256) Cb[(long)row * 256 + col + j] = f2b(v);
            else          Cz[(long)row * 256 + (col - 256 + j)] = f2b(siluf(v));
        }
    }
}

// ---------------------------------------------------------------------------
// Scan pass 1 (s-split, 512 threads, LCH=32): lane pair (2d,2d+1) handles
// s-halves of channel d.  Local recurrence from h=0 -> record (h_end, sumdt).
// ---------------------------------------------------------------------------
__global__ __launch_bounds__(512) void scan1_k(
    const unsigned short* __restrict__ dtb, const unsigned short* __restrict__ xcb,
    const float* __restrict__ bcb, const float* __restrict__ Alog,
    float* __restrict__ recbuf, int layer)
{
    const int c = blockIdx.x, b = blockIdx.y, br = blockIdx.z;
    const int tid = threadIdx.x;
    const int d = tid >> 1, sh = tid & 1, s0 = sh << 3;
    const float* Ap = Alog + ((long)(br * NLAY + layer) * DINNER + d) * DSTATE + s0;
    float Aa[8]; bool pw = true;
    #pragma unroll
    for (int k = 0; k < 8; ++k) {
        Aa[k] = -__expf(Ap[k]);
        pw = pw && (fabsf(Aa[k] + (float)(s0 + k + 1)) < 1e-3f);
    }
    const long rbase = (long)br * BT + (long)b * Tk + (long)c * LCH;
    const unsigned short* dtp = dtb + rbase * DINNER + d;
    const unsigned short* xcp = xcb + rbase * DINNER + d;
    __shared__ float bcs[LCH * 32];
    if (tid < LCH * 8)
        ((float4*)bcs)[tid] = ((const float4*)(bcb + rbase * 32))[tid];
    float dtc[UF], xcc[UF];
    #pragma unroll
    for (int u = 0; u < UF; ++u) {
        dtc[u] = b2f(dtp[(long)u * DINNER]);
        xcc[u] = b2f(xcp[(long)u * DINNER]);
    }
    __syncthreads();
    float h[8];
    #pragma unroll
    for (int k = 0; k < 8; ++k) h[k] = 0.f;
    float sumdt = 0.f;
    for (int base = 0; base < LCH; base += UF) {
        const int nb = (base + UF < LCH) ? base + UF : base;
        float dtn[UF], xcn[UF];
        #pragma unroll
        for (int u = 0; u < UF; ++u) {
            dtn[u] = b2f(dtp[(long)(nb + u) * DINNER]);
            xcn[u] = b2f(xcp[(long)(nb + u) * DINNER]);
        }
        #pragma unroll
        for (int u = 0; u < UF; ++u) {
            const int t = base + u;
            const float dtv = dtc[u];
            const float dtxc = dtv * xcc[u];
            sumdt += dtv;
            float dA[8];
            if (pw) dA_pow8(__expf(-dtv), sh, dA);
            else {
                #pragma unroll
                for (int k = 0; k < 8; ++k) dA[k] = __expf(dtv * Aa[k]);
            }
            const float* bcT = bcs + t * 32 + s0;
            #pragma unroll
            for (int k = 0; k < 8; ++k)
                h[k] = fmaf(dA[k], h[k], dtxc * bcT[k]);
        }
        #pragma unroll
        for (int u = 0; u < UF; ++u) { dtc[u] = dtn[u]; xcc[u] = xcn[u]; }
    }
    float* sb = recbuf + (((long)(br * 4 + b) * (NCH - 1) + c) * 17) * 256 + d;
    #pragma unroll
    for (int k = 0; k < 8; ++k) sb[(s0 + k) * 256] = h[k];
    if (!sh) sb[16 * 256] = sumdt;
}

// ---------------------------------------------------------------------------
// Scan pass 3 (s-split, 512 threads, LCH=32).  LAST=1: emit per-chunk column
// partials part[(brb*NCH+c)][d] instead of storing yz.
// ---------------------------------------------------------------------------
template<int LAST>
__global__ __launch_bounds__(512) void scan3_k(
    const unsigned short* __restrict__ dtb, const unsigned short* __restrict__ xcb,
    const float* __restrict__ bcb, const unsigned short* __restrict__ zb,
    const float* __restrict__ Alog, const float* __restrict__ Dpar,
    const float* __restrict__ recbuf, unsigned short* __restrict__ yzb,
    float* __restrict__ part, int layer)
{
    const int c = blockIdx.x, b = blockIdx.y, br = blockIdx.z;
    const int tid = threadIdx.x;
    const int d = tid >> 1, sh = tid & 1, s0 = sh << 3;
    const float* Ap = Alog + ((long)(br * NLAY + layer) * DINNER + d) * DSTATE + s0;
    float Aa[8]; bool pw = true;
    #pragma unroll
    for (int k = 0; k < 8; ++k) {
        Aa[k] = -__expf(Ap[k]);
        pw = pw && (fabsf(Aa[k] + (float)(s0 + k + 1)) < 1e-3f);
    }
    float h[8];
    #pragma unroll
    for (int k = 0; k < 8; ++k) h[k] = 0.f;
    if (c > 0) {
        const float* recB = recbuf + ((long)(br * 4 + b) * (NCH - 1)) * 17 * 256 + d;
        float rh[8], rs;
        #pragma unroll
        for (int k = 0; k < 8; ++k) rh[k] = recB[(s0 + k) * 256];
        rs = recB[16 * 256];
        for (int cc = 0; cc < c; ++cc) {
            float nh[8], ns = 0.f;
            if (cc + 1 < c) {
                const float* r2 = recB + (long)(cc + 1) * 17 * 256;
                #pragma unroll
                for (int k = 0; k < 8; ++k) nh[k] = r2[(s0 + k) * 256];
                ns = r2[16 * 256];
            } else {
                #pragma unroll
                for (int k = 0; k < 8; ++k) nh[k] = 0.f;
            }
            float P[8];
            if (pw) dA_pow8(__expf(-rs), sh, P);
            else {
                #pragma unroll
                for (int k = 0; k < 8; ++k) P[k] = __expf(rs * Aa[k]);
            }
            #pragma unroll
            for (int k = 0; k < 8; ++k) h[k] = fmaf(h[k], P[k], rh[k]);
            #pragma unroll
            for (int k = 0; k < 8; ++k) rh[k] = nh[k];
            rs = ns;
        }
    }
    const float Dp = Dpar[(br * NLAY + layer) * DINNER + d];
    const long rbase = (long)br * BT + (long)b * Tk + (long)c * LCH;
    const unsigned short* dtp = dtb + rbase * DINNER + d;
    const unsigned short* xcp = xcb + rbase * DINNER + d;
    const unsigned short* zp  = zb  + rbase * DINNER + d;
    unsigned short* yp = yzb + rbase * DINNER + d;
    __shared__ float bcs[LCH * 32];
    if (tid < LCH * 8)
        ((float4*)bcs)[tid] = ((const float4*)(bcb + rbase * 32))[tid];
    float dtc[UF], xcc[UF], zc[UF];
    #pragma unroll
    for (int u = 0; u < UF; ++u) {
        dtc[u] = b2f(dtp[(long)u * DINNER]);
        xcc[u] = b2f(xcp[(long)u * DINNER]);
        zc[u]  = b2f(zp[(long)u * DINNER]);
    }
    __syncthreads();
    float ysum = 0.f;
    for (int base = 0; base < LCH; base += UF) {
        const int nb = (base + UF < LCH) ? base + UF : base;
        float dtn[UF], xcn[UF], zn[UF];
        #pragma unroll
        for (int u = 0; u < UF; ++u) {
            dtn[u] = b2f(dtp[(long)(nb + u) * DINNER]);
            xcn[u] = b2f(xcp[(long)(nb + u) * DINNER]);
            zn[u]  = b2f(zp[(long)(nb + u) * DINNER]);
        }
        #pragma unroll
        for (int u = 0; u < UF; ++u) {
            const int t = base + u;
            const float dtv = dtc[u], xcv = xcc[u];
            const float dtxc = dtv * xcv;
            float dA[8];
            if (pw) dA_pow8(__expf(-dtv), sh, dA);
            else {
                #pragma unroll
                for (int k = 0; k < 8; ++k) dA[k] = __expf(dtv * Aa[k]);
            }
            const float* bcT = bcs + t * 32 + s0;
            #pragma unroll
            for (int k = 0; k < 8; ++k)
                h[k] = fmaf(dA[k], h[k], dtxc * bcT[k]);
            float y0 = 0.f, y1 = 0.f;
            const float* cT = bcs + t * 32 + 16 + s0;
            #pragma unroll
            for (int k = 0; k < 8; k += 2) {
                y0 = fmaf(h[k+0], cT[k+0], y0);
                y1 = fmaf(h[k+1], cT[k+1], y1);
            }
            const float yp_ = y0 + y1;
            const float ytot = yp_ + __shfl_xor(yp_, 1);
            const float y = ytot + Dp * xcv;
            if (LAST) {
                ysum += y * zc[u];
            } else if (!sh) {
                yp[(long)t * DINNER] = f2b(y * zc[u]);
            }
        }
        #pragma unroll
        for (int u = 0; u < UF; ++u) { dtc[u] = dtn[u]; xcc[u] = xcn[u]; zc[u] = zn[u]; }
    }
    if (LAST && !sh)
        part[((long)(br * 4 + b) * NCH + c) * 256 + d] = ysum;
}

// ---------------------------------------------------------------------------
// Stage 2: z_t[brb] = mean(yz) @ Wcomb + bop.  16 blocks; NCH chunk-partials.
// ---------------------------------------------------------------------------
__global__ __launch_bounds__(256) void csum2_k(
    const float* __restrict__ part, const float* __restrict__ Wcomb,
    const float* __restrict__ bop, float* __restrict__ outzt)
{
    const int brb = blockIdx.x, br = brb >> 2;
    const int tid = threadIdx.x;
    __shared__ float vm[256];
    __shared__ float red[4][64];
    float s = 0.f;
    for (int ch = 0; ch < NCH; ++ch) s += part[((long)brb * NCH + ch) * 256 + tid];
    vm[tid] = s * (1.0f / Tk);
    __syncthreads();
    const float* Wc = Wcomb + (long)br * DINNER * EMBEDk;
    const int col = tid & 63, seg = tid >> 6;
    float a = 0.f;
    #pragma unroll 8
    for (int k = seg * 64; k < seg * 64 + 64; ++k)
        a = fmaf(vm[k], Wc[(long)k * EMBEDk + col], a);
    red[seg][col] = a;
    __syncthreads();
    if (tid < 64)
        outzt[brb * EMBEDk + tid] =
            red[0][tid] + red[1][tid] + red[2][tid] + red[3][tid] + bop[br * EMBEDk + tid];
}

// ---------------------------------------------------------------------------
// Lorentz epilogue.
// ---------------------------------------------------------------------------
__global__ __launch_bounds__(64) void final_k(
    const float* __restrict__ zt, float* __restrict__ out, const float* __restrict__ eff)
{
    const float es = tanhf(eff[0]);
    __shared__ float us[NBR][Bk][EMBEDk];
    const int t = threadIdx.x;
    if (t < 16) {
        const int br = t >> 2, b = t & 3;
        const float* z = zt + br * (Bk * EMBEDk) + b * EMBEDk;
        float n2 = 0.f;
        for (int e = 0; e < EMBEDk; ++e) { float v = z[e] * es; n2 = fmaf(v, v, n2); }
        const float n  = sqrtf(n2);
        const float nc = fminf(fmaxf(n, EPSF), MAXNF);
        const float sc = nc / fmaxf(n, EPSF);
        const float sh = sinhf(nc) / nc;
        const float fac = es * sc * sh;
        float* zh = out + 1024 + br * (Bk * (EMBEDk + 1)) + b * (EMBEDk + 1);
        float sp2 = 0.f;
        for (int e = 0; e < EMBEDk; ++e) {
            float spv = z[e] * fac;
            sp2 = fmaf(spv, spv, sp2);
            zh[1 + e] = spv;
            us[br][b][e] = spv;
        }
        const float t0 = sqrtf(1.f + sp2);
        zh[0] = t0;
        const float dd  = acoshf(fmaxf(t0, 1.f + EPSF));
        const float spn = fmaxf(sqrtf(sp2), EPSF);
        const float rr  = dd / spn;
        for (int e = 0; e < EMBEDk; ++e) us[br][b][e] *= rr;
    }
    __syncthreads();
    if (t < 4) {
        const int b = t;
        float ct[EMBEDk];
        float* cto = out + 2064 + b * EMBEDk;
        for (int e = 0; e < EMBEDk; ++e) {
            float v = us[0][b][e] + us[1][b][e] + us[2][b][e] + us[3][b][e];
            ct[e] = v; cto[e] = v;
        }
        float n2 = 0.f;
        for (int e = 0; e < EMBEDk; ++e) { float v = ct[e] * es; n2 = fmaf(v, v, n2); }
        const float n  = sqrtf(n2);
        const float nc = fminf(fmaxf(n, EPSF), MAXNF);
        const float sc = nc / fmaxf(n, EPSF);
        const float sh = sinhf(nc) / nc;
        const float fac = es * sc * sh;
        float* ch = out + 2320 + b * (EMBEDk + 1);
        float sp2 = 0.f;
        for (int e = 0; e < EMBEDk; ++e) {
            float spv = ct[e] * fac;
            sp2 = fmaf(spv, spv, sp2);
            ch[1 + e] = spv;
        }
        ch[0] = sqrtf(1.f + sp2);
    }
}

extern "C" void kernel_launch(void* const* d_in, const int* in_sizes, int n_in,
                              void* d_out, int out_size, void* d_ws, size_t ws_size,
                              hipStream_t stream)
{
    const float* X0 = (const float*)d_in[0];
    const float* X1 = (const float*)d_in[1];
    const float* X2 = (const float*)d_in[2];
    const float* X3 = (const float*)d_in[3];
    const float* W_ip   = (const float*)d_in[4];
    const float* b_ip   = (const float*)d_in[5];
    const float* W_in   = (const float*)d_in[6];
    const float* conv_w = (const float*)d_in[7];
    const float* conv_b = (const float*)d_in[8];
    const float* W_x    = (const float*)d_in[9];
    const float* W_dt   = (const float*)d_in[10];
    const float* b_dt   = (const float*)d_in[11];
    const float* A_log  = (const float*)d_in[12];
    const float* D_par  = (const float*)d_in[13];
    const float* W_out  = (const float*)d_in[14];
    const float* W_op   = (const float*)d_in[15];
    const float* b_op   = (const float*)d_in[16];
    const float* eff    = (const float*)d_in[17];
    float* out = (float*)d_out;
    float* ws  = (float*)d_ws;

    // ---- workspace ----
    float* buf_bc = ws;                                        // 524,288 f32
    float* part   = buf_bc + (long)NBR * BT * 32;              // 16*NCH*256 f32
    float* recbuf = part + (long)16 * NCH * 256;               // 16*(NCH-1)*17*256 f32
    float* Weq    = recbuf + (long)16 * (NCH - 1) * 17 * 256;  // 67,584 f32
    float* Wcomb  = Weq + 4 * 33 * 512;                        // 65,536 f32
    unsigned short* xp_bf = (unsigned short*)(Wcomb + 4 * 256 * 64);
    unsigned short* xc_bf = xp_bf + (long)NBR * BT * DINNER;   // 8 MB each
    unsigned short* z_bf  = xc_bf + (long)NBR * BT * DINNER;
    unsigned short* dt_bf = z_bf  + (long)NBR * BT * DINNER;
    unsigned short* yz_bf = dt_bf + (long)NBR * BT * DINNER;
    unsigned short* WfT   = yz_bf + (long)NBR * BT * DINNER;   // 8*512*256 u16
    unsigned short* WcT   = WfT   + (long)8 * 512 * DINNER;    // 12*384*256 u16

    // ---- weight prep (single launch: WfT, Weq, Wcomb, wcombT panels) ----
    sgemmWT_k<<<dim3(4, 8, 22), 256, 0, stream>>>(
        W_out, W_in, W_ip, b_ip, W_op, W_x, W_dt, WfT, Weq, Wcomb, WcT);

    // ---- layer 0 xz: x @ Weq + beq (fp32, K=32) ----
    xgemm0_k<<<dim3(BT / 64, 8, NBR), 256, 0, stream>>>(
        X0, X1, X2, X3, Weq, z_bf, xp_bf);

    for (int l = 0; l < NLAY; ++l) {
        if (l > 0) {
            bgemm_k<0><<<dim3(BT / 64, 4, NBR), 256, 0, stream>>>(
                yz_bf, (long)BT * DINNER, DINNER,
                WfT + (long)(l - 1) * 4 * 512 * DINNER, (long)512 * DINNER,
                xp_bf, (long)BT * DINNER,
                z_bf, (long)BT * DINNER,
                nullptr, 0, nullptr, 0);
        }
        // depthwise conv + silu (bf16 -> bf16), high-TLP
        conv_k<<<dim3((BT * DINNER) / (256 * 8), NBR), 256, 0, stream>>>(
            xp_bf, conv_w, conv_b, xc_bf, l);
        // dt = softplus(xc @ wc + b_dt) bf16; bc = xc @ wcBC f32  (N=384 padded)
        bgemm_k<3><<<dim3(BT / 64, 3, NBR), 256, 0, stream>>>(
            xc_bf, (long)BT * DINNER, DINNER,
            WcT + (long)l * NWB * DINNER, (long)NLAY * NWB * DINNER,
            dt_bf, (long)BT * DINNER,
            nullptr, 0,
            buf_bc, (long)BT * 32,
            b_dt + l * DINNER, (long)NLAY * DINNER);
        // chunked scan, s-split 512-thread blocks, LCH=32 (2x TLP, half chain)
        scan1_k<<<dim3(NCH - 1, Bk, NBR), 512, 0, stream>>>(
            dt_bf, xc_bf, buf_bc, A_log, recbuf, l);
        if (l < NLAY - 1) {
            scan3_k<0><<<dim3(NCH, Bk, NBR), 512, 0, stream>>>(
                dt_bf, xc_bf, buf_bc, z_bf, A_log, D_par, recbuf, yz_bf, nullptr, l);
        } else {
            scan3_k<1><<<dim3(NCH, Bk, NBR), 512, 0, stream>>>(
                dt_bf, xc_bf, buf_bc, z_bf, A_log, D_par, recbuf, yz_bf, part, l);
        }
    }

    // z_t = mean_t(yz) @ (Wout2 @ Wop) + bop
    csum2_k<<<16, 256, 0, stream>>>(part, Wcomb, b_op, out);
    final_k<<<1, 64, 0, stream>>>(out, out, eff);
}

// Round 10
// 419.187 us; speedup vs baseline: 1.1458x; 1.1458x over previous
//
#include <hip/hip_runtime.h>
#include <math.h>

#define NBR 4
#define NLAY 3
#define Bk 4
#define Tk 1024
#define DIN 32
#define DMODEL 128
#define DINNER 256
#define DSTATE 16
#define DTRANK 8
#define EMBEDk 64
#define BT (Bk*Tk)          /* 4096 rows per branch */
#define EPSF 1e-7f
#define MAXNF 10.0f
#define LCH 64              /* scan chunk length (measured optimum) */
#define NCH (Tk/LCH)        /* 16 chunks */
#define UF 8                /* t-loop batch (latency amortization) */
#define NWB 384             /* dt|bc panel rows: 256 dt + 32 bc + 96 pad */

typedef __bf16 bf16x8 __attribute__((ext_vector_type(8)));
typedef float  f32x4  __attribute__((ext_vector_type(4)));
typedef unsigned short u16x8 __attribute__((ext_vector_type(8)));
typedef unsigned short u16x4 __attribute__((ext_vector_type(4)));

__device__ __forceinline__ float siluf(float x){ return x / (1.f + __expf(-x)); }
__device__ __forceinline__ float softplusf(float x){ return (x > 20.f) ? x : log1pf(__expf(x)); }
__device__ __forceinline__ unsigned short f2b(float x){
    union { float f; unsigned u; } v; v.f = x;
    unsigned r = v.u + 0x7FFF + ((v.u >> 16) & 1);
    return (unsigned short)(r >> 16);
}
__device__ __forceinline__ float b2f(unsigned short u){
    union { unsigned u; float f; } v; v.u = ((unsigned)u) << 16; return v.f;
}

// async global->LDS, 16 B per lane; LDS dest = wave-uniform base + lane*16
__device__ __forceinline__ void gll16(const void* g, void* l){
    __builtin_amdgcn_global_load_lds(
        (const __attribute__((address_space(1))) unsigned int*)g,
        (__attribute__((address_space(3))) unsigned int*)l,
        16, 0, 0);
}

// 8 powers for the s-split: dA[k] = q^(s0+k+1), s0 = sh*8.  Branchless.
__device__ __forceinline__ void dA_pow8(float q, int sh, float* dA){
    const float q2 = q * q, q4 = q2 * q2, q8 = q4 * q4;
    const float f = sh ? q8 : 1.0f;
    dA[0] = q * f;       dA[1] = q2 * f;
    dA[2] = q2 * q * f;  dA[3] = q4 * f;
    dA[4] = q4 * q * f;  dA[5] = q4 * q2 * f;
    dA[6] = q4 * q2 * q * f; dA[7] = q8 * f;
}

// ---------------------------------------------------------------------------
// bf16 MFMA GEMM, 64x128 tile (two 64-col subtiles per staged A-tile).
// A bf16 [M][K]; B TRANSPOSED bf16 [N][K].  4 waves, 256 thr, 24 KB LDS.
// MODE 0 (xz):  col<256 -> Cu0 bf16 (xp); col>=256 -> Cu1 bf16 silu (z)
// MODE 3 (dtbc): col<256 -> Cu0 bf16 softplus(v+bias) (dt); 256..287 -> Cf (bc)
// ---------------------------------------------------------------------------
template<int MODE>
__global__ __launch_bounds__(256) void bgemm_k(
    const unsigned short* __restrict__ Ab, long aBr, int K,
    const unsigned short* __restrict__ Bt, long bBr,
    unsigned short* __restrict__ Cu0, long cu0Br,
    unsigned short* __restrict__ Cu1, long cu1Br,
    float* __restrict__ Cf, long cfBr,
    const float* __restrict__ bias, long biasBr)
{
    const int br = blockIdx.z;
    Ab += (long)br * aBr;
    Bt += (long)br * bBr;
    Cu0 += (long)br * cu0Br;
    if (MODE == 0) Cu1 += (long)br * cu1Br;
    if (MODE == 3) { Cf += (long)br * cfBr; bias += (long)br * biasBr; }
    const int m0 = blockIdx.x * 64, n0 = blockIdx.y * 128;
    __shared__ __align__(16) unsigned short As[8 * 64 * 8];    // 8 KB  [kch][m][8]
    __shared__ __align__(16) unsigned short Bs[8 * 128 * 8];   // 16 KB [kch][n][8]
    const int tid = threadIdx.x;
    const int lane = tid & 63, w = tid >> 6;
    const int wm = w >> 1, wn = w & 1;
    const int quad = lane >> 4, l15 = lane & 15;
    f32x4 acc[2][4];
    #pragma unroll
    for (int nt = 0; nt < 2; ++nt)
        #pragma unroll
        for (int e = 0; e < 4; ++e) { f32x4 zz = {0,0,0,0}; acc[nt][e] = zz; }
    for (int kc = 0; kc < K; kc += 64) {
        #pragma unroll
        for (int it = 0; it < 2; ++it) {
            const int kch = w + it * 4;   // wave-uniform
            gll16(Ab + (long)(m0 + lane) * K + kc + kch * 8, &As[(kch * 64) * 8]);
        }
        #pragma unroll
        for (int it = 0; it < 4; ++it) {
            const int ub = w * 256 + it * 64;   // wave-uniform
            const int u = ub + lane;
            const int kch = u >> 7, nrow = u & 127;
            gll16(Bt + (long)(n0 + nrow) * K + kc + kch * 8, &Bs[ub * 8]);
        }
        __syncthreads();
        #pragma unroll
        for (int k0 = 0; k0 < 64; k0 += 32) {
            const int kch = (k0 >> 3) + quad;
            bf16x8 a0 = *(const bf16x8*)&As[(kch * 64 + wm * 32 +      l15) * 8];
            bf16x8 a1 = *(const bf16x8*)&As[(kch * 64 + wm * 32 + 16 + l15) * 8];
            #pragma unroll
            for (int nt = 0; nt < 2; ++nt) {
                bf16x8 b0 = *(const bf16x8*)&Bs[(kch * 128 + nt * 64 + wn * 32 +      l15) * 8];
                bf16x8 b1 = *(const bf16x8*)&Bs[(kch * 128 + nt * 64 + wn * 32 + 16 + l15) * 8];
                acc[nt][0] = __builtin_amdgcn_mfma_f32_16x16x32_bf16(a0, b0, acc[nt][0], 0, 0, 0);
                acc[nt][1] = __builtin_amdgcn_mfma_f32_16x16x32_bf16(a0, b1, acc[nt][1], 0, 0, 0);
                acc[nt][2] = __builtin_amdgcn_mfma_f32_16x16x32_bf16(a1, b0, acc[nt][2], 0, 0, 0);
                acc[nt][3] = __builtin_amdgcn_mfma_f32_16x16x32_bf16(a1, b1, acc[nt][3], 0, 0, 0);
            }
        }
        __syncthreads();
    }
    #pragma unroll
    for (int nt = 0; nt < 2; ++nt) {
        #pragma unroll
        for (int e = 0; e < 4; ++e) {
            const f32x4 a = acc[nt][e];
            const int msub = (e >> 1) * 16, nsub = (e & 1) * 16;
            const int col = n0 + nt * 64 + wn * 32 + nsub + l15;
            #pragma unroll
            for (int r = 0; r < 4; ++r) {
                const int row = m0 + wm * 32 + msub + quad * 4 + r;
                const float v = a[r];
                if (MODE == 0) {
                    if (col < 256) Cu0[(long)row * 256 + col] = f2b(v);
                    else           Cu1[(long)row * 256 + (col - 256)] = f2b(siluf(v));
                } else {
                    if (col < 256)      Cu0[(long)row * 256 + col] = f2b(softplusf(v + bias[col]));
                    else if (col < 288) Cf[(long)row * 32 + (col - 256)] = v;
                }
            }
        }
    }
}

// ---------------------------------------------------------------------------
// Depthwise causal conv (4 taps) + bias + silu: bf16 in -> bf16 out.
// 8 channels / thread, u16x8 loads; 2048 blocks (high TLP).
// ---------------------------------------------------------------------------
__global__ __launch_bounds__(256) void conv_k(
    const unsigned short* __restrict__ xp, const float* __restrict__ cw,
    const float* __restrict__ cb, unsigned short* __restrict__ xcb, int layer)
{
    const int br = blockIdx.y;
    const long base = (long)br * BT * DINNER;
    const long idx8 = ((long)blockIdx.x * 256 + threadIdx.x) * 8;
    const int d0 = (int)(idx8 & (DINNER - 1));
    const long row = idx8 >> 8;
    const int t = (int)(row & (Tk - 1));
    const float* cwp = cw + ((long)(br * NLAY + layer) * DINNER + d0) * 4;
    const float* cbp = cb + (long)(br * NLAY + layer) * DINNER + d0;
    u16x8 in[4];
    #pragma unroll
    for (int k = 0; k < 4; ++k) {
        const int tt = t + k - 3;
        if (tt >= 0) {
            in[k] = *(const u16x8*)(xp + base + idx8 + (long)(k - 3) * DINNER);
        } else {
            #pragma unroll
            for (int j = 0; j < 8; ++j) in[k][j] = 0;
        }
    }
    u16x8 o;
    #pragma unroll
    for (int j = 0; j < 8; ++j) {
        float acc = cbp[j];
        #pragma unroll
        for (int k = 0; k < 4; ++k)
            acc = fmaf(b2f(in[k][j]), cwp[j * 4 + k], acc);
        o[j] = f2b(siluf(acc));
    }
    *(u16x8*)(xcb + base + idx8) = o;
}

// ---------------------------------------------------------------------------
// Weight prep GEMM.
//  z<8: WfT[z] = bf16((Wout_p @ Win_{p+1})^T).  z==8: Weq = [Wip;bip]@Win_0.
//  z==9: Wcomb = Wout_2 @ Wop.  z in 10..21: wcombT panel for bl=z-10.
// ---------------------------------------------------------------------------
__global__ __launch_bounds__(256) void sgemmWT_k(
    const float* __restrict__ Wout, const float* __restrict__ Win,
    const float* __restrict__ Wip, const float* __restrict__ bip,
    const float* __restrict__ Wop,
    const float* __restrict__ Wx, const float* __restrict__ Wdt,
    unsigned short* __restrict__ WfT, float* __restrict__ Weq,
    float* __restrict__ Wcomb, unsigned short* __restrict__ WcT)
{
    const int z = blockIdx.z;
    const int tid = threadIdx.x;
    const int tx = tid & 15, ty = tid >> 4;
    __shared__ float As_[32][68];
    __shared__ float Bs_[32][68];
    float acc[4][4] = {};
    if (z < 8) {
        const int p = z >> 2, br = z & 3;
        const float* A  = Wout + (long)(br * NLAY + p) * DINNER * DMODEL;
        const float* Bw = Win  + (long)(br * NLAY + p + 1) * DMODEL * 512;
        const int m0 = blockIdx.x * 64, n0 = blockIdx.y * 64;
        for (int kc = 0; kc < DMODEL; kc += 32) {
            #pragma unroll
            for (int it = 0; it < 2; ++it) {
                int id = tid + it * 256;
                int r = id >> 3, c4 = (id & 7) << 2;
                float4 v = *(const float4*)(A + (long)(m0 + r) * DMODEL + kc + c4);
                As_[c4+0][r] = v.x; As_[c4+1][r] = v.y; As_[c4+2][r] = v.z; As_[c4+3][r] = v.w;
                int rb = id >> 4, cb = (id & 15) << 2;
                *(float4*)&Bs_[rb][cb] = *(const float4*)(Bw + (long)(kc + rb) * 512 + n0 + cb);
            }
            __syncthreads();
            #pragma unroll
            for (int kk = 0; kk < 32; ++kk) {
                float4 a4 = *(const float4*)&As_[kk][ty << 2];
                float4 b4 = *(const float4*)&Bs_[kk][tx << 2];
                float av[4] = {a4.x, a4.y, a4.z, a4.w};
                float bv[4] = {b4.x, b4.y, b4.z, b4.w};
                #pragma unroll
                for (int i = 0; i < 4; ++i)
                    #pragma unroll
                    for (int j = 0; j < 4; ++j)
                        acc[i][j] = fmaf(av[i], bv[j], acc[i][j]);
            }
            __syncthreads();
        }
        unsigned short* o = WfT + (long)z * 512 * 256;
        const int row0 = m0 + (ty << 2), col = n0 + (tx << 2);
        #pragma unroll
        for (int j = 0; j < 4; ++j) {
            u16x4 v;
            #pragma unroll
            for (int i = 0; i < 4; ++i) v[i] = f2b(acc[i][j]);
            *(u16x4*)(o + (long)(col + j) * 256 + row0) = v;
        }
    } else if (z == 8) {
        const int br = blockIdx.x;
        const float* A  = Wip + (long)br * DIN * DMODEL;
        const float* bp = bip + (long)br * DMODEL;
        const float* Bw = Win + (long)br * NLAY * DMODEL * 512;
        const int n0 = blockIdx.y * 64;
        for (int kc = 0; kc < DMODEL; kc += 32) {
            #pragma unroll
            for (int it = 0; it < 2; ++it) {
                int id = tid + it * 256;
                int r = id >> 3, c4 = (id & 7) << 2;
                float4 v;
                if (r < 32)       v = *(const float4*)(A + (long)r * DMODEL + kc + c4);
                else if (r == 32) v = *(const float4*)(bp + kc + c4);
                else              { v.x = 0.f; v.y = 0.f; v.z = 0.f; v.w = 0.f; }
                As_[c4+0][r] = v.x; As_[c4+1][r] = v.y; As_[c4+2][r] = v.z; As_[c4+3][r] = v.w;
                int rb = id >> 4, cb = (id & 15) << 2;
                *(float4*)&Bs_[rb][cb] = *(const float4*)(Bw + (long)(kc + rb) * 512 + n0 + cb);
            }
            __syncthreads();
            #pragma unroll
            for (int kk = 0; kk < 32; ++kk) {
                float4 a4 = *(const float4*)&As_[kk][ty << 2];
                float4 b4 = *(const float4*)&Bs_[kk][tx << 2];
                float av[4] = {a4.x, a4.y, a4.z, a4.w};
                float bv[4] = {b4.x, b4.y, b4.z, b4.w};
                #pragma unroll
                for (int i = 0; i < 4; ++i)
                    #pragma unroll
                    for (int j = 0; j < 4; ++j)
                        acc[i][j] = fmaf(av[i], bv[j], acc[i][j]);
            }
            __syncthreads();
        }
        float* C = Weq + (long)br * 33 * 512;
        const int col = n0 + (tx << 2);
        #pragma unroll
        for (int i = 0; i < 4; ++i) {
            const int row = (ty << 2) + i;
            if (row < 33) {
                float4 v4; v4.x = acc[i][0]; v4.y = acc[i][1]; v4.z = acc[i][2]; v4.w = acc[i][3];
                *(float4*)(C + (long)row * 512 + col) = v4;
            }
        }
    } else if (z == 9) {
        if (blockIdx.y >= 4) return;
        const int br = blockIdx.y;
        const float* A  = Wout + (long)(br * NLAY + 2) * DINNER * DMODEL;
        const float* Bw = Wop  + (long)br * DMODEL * EMBEDk;
        const int m0 = blockIdx.x * 64;
        for (int kc = 0; kc < DMODEL; kc += 32) {
            #pragma unroll
            for (int it = 0; it < 2; ++it) {
                int id = tid + it * 256;
                int r = id >> 3, c4 = (id & 7) << 2;
                float4 v = *(const float4*)(A + (long)(m0 + r) * DMODEL + kc + c4);
                As_[c4+0][r] = v.x; As_[c4+1][r] = v.y; As_[c4+2][r] = v.z; As_[c4+3][r] = v.w;
                int rb = id >> 4, cb = (id & 15) << 2;
                if (cb < 64)
                    *(float4*)&Bs_[rb][cb] = *(const float4*)(Bw + (long)(kc + rb) * EMBEDk + cb);
            }
            __syncthreads();
            #pragma unroll
            for (int kk = 0; kk < 32; ++kk) {
                float4 a4 = *(const float4*)&As_[kk][ty << 2];
                float4 b4 = *(const float4*)&Bs_[kk][tx << 2];
                float av[4] = {a4.x, a4.y, a4.z, a4.w};
                float bv[4] = {b4.x, b4.y, b4.z, b4.w};
                #pragma unroll
                for (int i = 0; i < 4; ++i)
                    #pragma unroll
                    for (int j = 0; j < 4; ++j)
                        acc[i][j] = fmaf(av[i], bv[j], acc[i][j]);
            }
            __syncthreads();
        }
        float* C = Wcomb + (long)br * DINNER * EMBEDk;
        const int col = tx << 2;
        #pragma unroll
        for (int i = 0; i < 4; ++i) {
            const int row = m0 + (ty << 2) + i;
            float4 v4; v4.x = acc[i][0]; v4.y = acc[i][1]; v4.z = acc[i][2]; v4.w = acc[i][3];
            *(float4*)(C + (long)row * EMBEDk + col) = v4;
        }
    } else {   // z in 10..21: wcombT panel for bl = z-10, 12 rows/block
        const int bl = z - 10;
        const int base = (blockIdx.x * 8 + blockIdx.y) * 12;
        const float* WxP = Wx + (long)bl * DINNER * 40;
        const float* WdtP = Wdt + (long)bl * DTRANK * DINNER;
        unsigned short* o = WcT + (long)bl * NWB * DINNER;
        #pragma unroll
        for (int i = 0; i < 12; ++i) {
            const int n = base + i;
            float v;
            if (n < 256) {
                float s = 0.f;
                #pragma unroll
                for (int r = 0; r < 8; ++r) s = fmaf(WxP[tid * 40 + r], WdtP[r * DINNER + n], s);
                v = s;
            } else if (n < 288) {
                v = WxP[tid * 40 + 8 + (n - 256)];
            } else {
                v = 0.f;
            }
            o[(long)n * DINNER + tid] = f2b(v);
        }
    }
}

// ---------------------------------------------------------------------------
// Layer-0 xz: fp32 GEMM x @ Weq + beq (K=32).  col<256 -> xp bf16; else z bf16.
// ---------------------------------------------------------------------------
__global__ __launch_bounds__(256) void xgemm0_k(
    const float* __restrict__ A0, const float* __restrict__ A1,
    const float* __restrict__ A2, const float* __restrict__ A3,
    const float* __restrict__ Weq,
    unsigned short* __restrict__ zb, unsigned short* __restrict__ xpb)
{
    const int br = blockIdx.z;
    const float* A = (br == 1) ? A1 : (br == 2) ? A2 : (br == 3) ? A3 : A0;
    const float* W = Weq + (long)br * 33 * 512;
    unsigned short* Cz = zb + (long)br * BT * DINNER;
    unsigned short* Cb = xpb + (long)br * BT * DINNER;
    const int m0 = blockIdx.x * 64, n0 = blockIdx.y * 64;
    __shared__ float As_[32][68];
    __shared__ float Bs_[32][68];
    const int tid = threadIdx.x;
    const int tx = tid & 15, ty = tid >> 4;
    float acc[4][4] = {};
    {
        #pragma unroll
        for (int it = 0; it < 2; ++it) {
            int id = tid + it * 256;
            int r = id >> 3, c4 = (id & 7) << 2;
            float4 v = *(const float4*)(A + (long)(m0 + r) * DIN + c4);
            As_[c4+0][r] = v.x; As_[c4+1][r] = v.y; As_[c4+2][r] = v.z; As_[c4+3][r] = v.w;
            int rb = id >> 4, cb = (id & 15) << 2;
            *(float4*)&Bs_[rb][cb] = *(const float4*)(W + (long)rb * 512 + n0 + cb);
        }
        __syncthreads();
        #pragma unroll
        for (int kk = 0; kk < 32; ++kk) {
            float4 a4 = *(const float4*)&As_[kk][ty << 2];
            float4 b4 = *(const float4*)&Bs_[kk][tx << 2];
            float av[4] = {a4.x, a4.y, a4.z, a4.w};
            float bv[4] = {b4.x, b4.y, b4.z, b4.w};
            #pragma unroll
            for (int i = 0; i < 4; ++i)
                #pragma unroll
                for (int j = 0; j < 4; ++j)
                    acc[i][j] = fmaf(av[i], bv[j], acc[i][j]);
        }
    }
    const int col = n0 + (tx << 2);
    float be[4];
    #pragma unroll
    for (int j = 0; j < 4; ++j) be[j] = W[32 * 512 + col + j];
    #pragma unroll
    for (int i = 0; i < 4; ++i) {
        const int row = m0 + (ty << 2) + i;
        #pragma unroll
        for (int j = 0; j < 4; ++j) {
            const float v = acc[i][j] + be[j];
            if (n0 < 256) Cb[(long)row * 256 + col + j] = f2b(v);
            else          Cz[(long)row * 256 + (col - 256 + j)] = f2b(siluf(v));
        }
    }
}

// ---------------------------------------------------------------------------
// Scan pass 1 (s-split, 512 threads).
// ---------------------------------------------------------------------------
__global__ __launch_bounds__(512) void scan1_k(
    const unsigned short* __restrict__ dtb, const unsigned short* __restrict__ xcb,
    const float* __restrict__ bcb, const float* __restrict__ Alog,
    float* __restrict__ recbuf, int layer)
{
    const int c = blockIdx.x, b = blockIdx.y, br = blockIdx.z;
    const int tid = threadIdx.x;
    const int d = tid >> 1, sh = tid & 1, s0 = sh << 3;
    const float* Ap = Alog + ((long)(br * NLAY + layer) * DINNER + d) * DSTATE + s0;
    float Aa[8]; bool pw = true;
    #pragma unroll
    for (int k = 0; k < 8; ++k) {
        Aa[k] = -__expf(Ap[k]);
        pw = pw && (fabsf(Aa[k] + (float)(s0 + k + 1)) < 1e-3f);
    }
    const long rbase = (long)br * BT + (long)b * Tk + (long)c * LCH;
    const unsigned short* dtp = dtb + rbase * DINNER + d;
    const unsigned short* xcp = xcb + rbase * DINNER + d;
    __shared__ float bcs[LCH * 32];
    ((float4*)bcs)[tid] = ((const float4*)(bcb + rbase * 32))[tid];
    float dtc[UF], xcc[UF];
    #pragma unroll
    for (int u = 0; u < UF; ++u) {
        dtc[u] = b2f(dtp[(long)u * DINNER]);
        xcc[u] = b2f(xcp[(long)u * DINNER]);
    }
    __syncthreads();
    float h[8];
    #pragma unroll
    for (int k = 0; k < 8; ++k) h[k] = 0.f;
    float sumdt = 0.f;
    for (int base = 0; base < LCH; base += UF) {
        const int nb = (base + UF < LCH) ? base + UF : base;
        float dtn[UF], xcn[UF];
        #pragma unroll
        for (int u = 0; u < UF; ++u) {
            dtn[u] = b2f(dtp[(long)(nb + u) * DINNER]);
            xcn[u] = b2f(xcp[(long)(nb + u) * DINNER]);
        }
        #pragma unroll
        for (int u = 0; u < UF; ++u) {
            const int t = base + u;
            const float dtv = dtc[u];
            const float dtxc = dtv * xcc[u];
            sumdt += dtv;
            float dA[8];
            if (pw) dA_pow8(__expf(-dtv), sh, dA);
            else {
                #pragma unroll
                for (int k = 0; k < 8; ++k) dA[k] = __expf(dtv * Aa[k]);
            }
            const float* bcT = bcs + t * 32 + s0;
            #pragma unroll
            for (int k = 0; k < 8; ++k)
                h[k] = fmaf(dA[k], h[k], dtxc * bcT[k]);
        }
        #pragma unroll
        for (int u = 0; u < UF; ++u) { dtc[u] = dtn[u]; xcc[u] = xcn[u]; }
    }
    float* sb = recbuf + (((long)(br * 4 + b) * (NCH - 1) + c) * 17) * 256 + d;
    #pragma unroll
    for (int k = 0; k < 8; ++k) sb[(s0 + k) * 256] = h[k];
    if (!sh) sb[16 * 256] = sumdt;
}

// ---------------------------------------------------------------------------
// Scan pass 3 (s-split, 512 threads).  LAST=1: emit per-chunk column partials.
// ---------------------------------------------------------------------------
template<int LAST>
__global__ __launch_bounds__(512) void scan3_k(
    const unsigned short* __restrict__ dtb, const unsigned short* __restrict__ xcb,
    const float* __restrict__ bcb, const unsigned short* __restrict__ zb,
    const float* __restrict__ Alog, const float* __restrict__ Dpar,
    const float* __restrict__ recbuf, unsigned short* __restrict__ yzb,
    float* __restrict__ part, int layer)
{
    const int c = blockIdx.x, b = blockIdx.y, br = blockIdx.z;
    const int tid = threadIdx.x;
    const int d = tid >> 1, sh = tid & 1, s0 = sh << 3;
    const float* Ap = Alog + ((long)(br * NLAY + layer) * DINNER + d) * DSTATE + s0;
    float Aa[8]; bool pw = true;
    #pragma unroll
    for (int k = 0; k < 8; ++k) {
        Aa[k] = -__expf(Ap[k]);
        pw = pw && (fabsf(Aa[k] + (float)(s0 + k + 1)) < 1e-3f);
    }
    float h[8];
    #pragma unroll
    for (int k = 0; k < 8; ++k) h[k] = 0.f;
    if (c > 0) {
        const float* recB = recbuf + ((long)(br * 4 + b) * (NCH - 1)) * 17 * 256 + d;
        float rh[8], rs;
        #pragma unroll
        for (int k = 0; k < 8; ++k) rh[k] = recB[(s0 + k) * 256];
        rs = recB[16 * 256];
        for (int cc = 0; cc < c; ++cc) {
            float nh[8], ns = 0.f;
            if (cc + 1 < c) {
                const float* r2 = recB + (long)(cc + 1) * 17 * 256;
                #pragma unroll
                for (int k = 0; k < 8; ++k) nh[k] = r2[(s0 + k) * 256];
                ns = r2[16 * 256];
            } else {
                #pragma unroll
                for (int k = 0; k < 8; ++k) nh[k] = 0.f;
            }
            float P[8];
            if (pw) dA_pow8(__expf(-rs), sh, P);
            else {
                #pragma unroll
                for (int k = 0; k < 8; ++k) P[k] = __expf(rs * Aa[k]);
            }
            #pragma unroll
            for (int k = 0; k < 8; ++k) h[k] = fmaf(h[k], P[k], rh[k]);
            #pragma unroll
            for (int k = 0; k < 8; ++k) rh[k] = nh[k];
            rs = ns;
        }
    }
    const float Dp = Dpar[(br * NLAY + layer) * DINNER + d];
    const long rbase = (long)br * BT + (long)b * Tk + (long)c * LCH;
    const unsigned short* dtp = dtb + rbase * DINNER + d;
    const unsigned short* xcp = xcb + rbase * DINNER + d;
    const unsigned short* zp  = zb  + rbase * DINNER + d;
    unsigned short* yp = yzb + rbase * DINNER + d;
    __shared__ float bcs[LCH * 32];
    ((float4*)bcs)[tid] = ((const float4*)(bcb + rbase * 32))[tid];
    float dtc[UF], xcc[UF], zc[UF];
    #pragma unroll
    for (int u = 0; u < UF; ++u) {
        dtc[u] = b2f(dtp[(long)u * DINNER]);
        xcc[u] = b2f(xcp[(long)u * DINNER]);
        zc[u]  = b2f(zp[(long)u * DINNER]);
    }
    __syncthreads();
    float ysum = 0.f;
    for (int base = 0; base < LCH; base += UF) {
        const int nb = (base + UF < LCH) ? base + UF : base;
        float dtn[UF], xcn[UF], zn[UF];
        #pragma unroll
        for (int u = 0; u < UF; ++u) {
            dtn[u] = b2f(dtp[(long)(nb + u) * DINNER]);
            xcn[u] = b2f(xcp[(long)(nb + u) * DINNER]);
            zn[u]  = b2f(zp[(long)(nb + u) * DINNER]);
        }
        #pragma unroll
        for (int u = 0; u < UF; ++u) {
            const int t = base + u;
            const float dtv = dtc[u], xcv = xcc[u];
            const float dtxc = dtv * xcv;
            float dA[8];
            if (pw) dA_pow8(__expf(-dtv), sh, dA);
            else {
                #pragma unroll
                for (int k = 0; k < 8; ++k) dA[k] = __expf(dtv * Aa[k]);
            }
            const float* bcT = bcs + t * 32 + s0;
            #pragma unroll
            for (int k = 0; k < 8; ++k)
                h[k] = fmaf(dA[k], h[k], dtxc * bcT[k]);
            float y0 = 0.f, y1 = 0.f;
            const float* cT = bcs + t * 32 + 16 + s0;
            #pragma unroll
            for (int k = 0; k < 8; k += 2) {
                y0 = fmaf(h[k+0], cT[k+0], y0);
                y1 = fmaf(h[k+1], cT[k+1], y1);
            }
            const float yp_ = y0 + y1;
            const float ytot = yp_ + __shfl_xor(yp_, 1);
            const float y = ytot + Dp * xcv;
            if (LAST) {
                ysum += y * zc[u];
            } else if (!sh) {
                yp[(long)t * DINNER] = f2b(y * zc[u]);
            }
        }
        #pragma unroll
        for (int u = 0; u < UF; ++u) { dtc[u] = dtn[u]; xcc[u] = xcn[u]; zc[u] = zn[u]; }
    }
    if (LAST && !sh)
        part[((long)(br * 4 + b) * 16 + c) * 256 + d] = ysum;
}

// ---------------------------------------------------------------------------
// Stage 2: z_t[brb] = mean(yz) @ Wcomb + bop.  16 blocks; 16 chunk-partials.
// ---------------------------------------------------------------------------
__global__ __launch_bounds__(256) void csum2_k(
    const float* __restrict__ part, const float* __restrict__ Wcomb,
    const float* __restrict__ bop, float* __restrict__ outzt)
{
    const int brb = blockIdx.x, br = brb >> 2;
    const int tid = threadIdx.x;
    __shared__ float vm[256];
    __shared__ float red[4][64];
    float s = 0.f;
    #pragma unroll
    for (int ch = 0; ch < 16; ++ch) s += part[((long)brb * 16 + ch) * 256 + tid];
    vm[tid] = s * (1.0f / Tk);
    __syncthreads();
    const float* Wc = Wcomb + (long)br * DINNER * EMBEDk;
    const int col = tid & 63, seg = tid >> 6;
    float a = 0.f;
    #pragma unroll 8
    for (int k = seg * 64; k < seg * 64 + 64; ++k)
        a = fmaf(vm[k], Wc[(long)k * EMBEDk + col], a);
    red[seg][col] = a;
    __syncthreads();
    if (tid < 64)
        outzt[brb * EMBEDk + tid] =
            red[0][tid] + red[1][tid] + red[2][tid] + red[3][tid] + bop[br * EMBEDk + tid];
}

// ---------------------------------------------------------------------------
// Lorentz epilogue.
// ---------------------------------------------------------------------------
__global__ __launch_bounds__(64) void final_k(
    const float* __restrict__ zt, float* __restrict__ out, const float* __restrict__ eff)
{
    const float es = tanhf(eff[0]);
    __shared__ float us[NBR][Bk][EMBEDk];
    const int t = threadIdx.x;
    if (t < 16) {
        const int br = t >> 2, b = t & 3;
        const float* z = zt + br * (Bk * EMBEDk) + b * EMBEDk;
        float n2 = 0.f;
        for (int e = 0; e < EMBEDk; ++e) { float v = z[e] * es; n2 = fmaf(v, v, n2); }
        const float n  = sqrtf(n2);
        const float nc = fminf(fmaxf(n, EPSF), MAXNF);
        const float sc = nc / fmaxf(n, EPSF);
        const float sh = sinhf(nc) / nc;
        const float fac = es * sc * sh;
        float* zh = out + 1024 + br * (Bk * (EMBEDk + 1)) + b * (EMBEDk + 1);
        float sp2 = 0.f;
        for (int e = 0; e < EMBEDk; ++e) {
            float spv = z[e] * fac;
            sp2 = fmaf(spv, spv, sp2);
            zh[1 + e] = spv;
            us[br][b][e] = spv;
        }
        const float t0 = sqrtf(1.f + sp2);
        zh[0] = t0;
        const float dd  = acoshf(fmaxf(t0, 1.f + EPSF));
        const float spn = fmaxf(sqrtf(sp2), EPSF);
        const float rr  = dd / spn;
        for (int e = 0; e < EMBEDk; ++e) us[br][b][e] *= rr;
    }
    __syncthreads();
    if (t < 4) {
        const int b = t;
        float ct[EMBEDk];
        float* cto = out + 2064 + b * EMBEDk;
        for (int e = 0; e < EMBEDk; ++e) {
            float v = us[0][b][e] + us[1][b][e] + us[2][b][e] + us[3][b][e];
            ct[e] = v; cto[e] = v;
        }
        float n2 = 0.f;
        for (int e = 0; e < EMBEDk; ++e) { float v = ct[e] * es; n2 = fmaf(v, v, n2); }
        const float n  = sqrtf(n2);
        const float nc = fminf(fmaxf(n, EPSF), MAXNF);
        const float sc = nc / fmaxf(n, EPSF);
        const float sh = sinhf(nc) / nc;
        const float fac = es * sc * sh;
        float* ch = out + 2320 + b * (EMBEDk + 1);
        float sp2 = 0.f;
        for (int e = 0; e < EMBEDk; ++e) {
            float spv = ct[e] * fac;
            sp2 = fmaf(spv, spv, sp2);
            ch[1 + e] = spv;
        }
        ch[0] = sqrtf(1.f + sp2);
    }
}

extern "C" void kernel_launch(void* const* d_in, const int* in_sizes, int n_in,
                              void* d_out, int out_size, void* d_ws, size_t ws_size,
                              hipStream_t stream)
{
    const float* X0 = (const float*)d_in[0];
    const float* X1 = (const float*)d_in[1];
    const float* X2 = (const float*)d_in[2];
    const float* X3 = (const float*)d_in[3];
    const float* W_ip   = (const float*)d_in[4];
    const float* b_ip   = (const float*)d_in[5];
    const float* W_in   = (const float*)d_in[6];
    const float* conv_w = (const float*)d_in[7];
    const float* conv_b = (const float*)d_in[8];
    const float* W_x    = (const float*)d_in[9];
    const float* W_dt   = (const float*)d_in[10];
    const float* b_dt   = (const float*)d_in[11];
    const float* A_log  = (const float*)d_in[12];
    const float* D_par  = (const float*)d_in[13];
    const float* W_out  = (const float*)d_in[14];
    const float* W_op   = (const float*)d_in[15];
    const float* b_op   = (const float*)d_in[16];
    const float* eff    = (const float*)d_in[17];
    float* out = (float*)d_out;
    float* ws  = (float*)d_ws;

    // ---- workspace ----
    float* buf_bc = ws;                                        // 524,288 f32
    float* part   = buf_bc + (long)NBR * BT * 32;              // 16*16*256 f32
    float* recbuf = part + 65536;                              // 16*15*17*256 f32
    float* Weq    = recbuf + (long)16 * (NCH - 1) * 17 * 256;  // 67,584 f32
    float* Wcomb  = Weq + 4 * 33 * 512;                        // 65,536 f32
    unsigned short* xp_bf = (unsigned short*)(Wcomb + 4 * 256 * 64);
    unsigned short* xc_bf = xp_bf + (long)NBR * BT * DINNER;   // 8 MB each
    unsigned short* z_bf  = xc_bf + (long)NBR * BT * DINNER;
    unsigned short* dt_bf = z_bf  + (long)NBR * BT * DINNER;
    unsigned short* yz_bf = dt_bf + (long)NBR * BT * DINNER;
    unsigned short* WfT   = yz_bf + (long)NBR * BT * DINNER;   // 8*512*256 u16
    unsigned short* WcT   = WfT   + (long)8 * 512 * DINNER;    // 12*384*256 u16

    // ---- weight prep (single launch: WfT, Weq, Wcomb, wcombT panels) ----
    sgemmWT_k<<<dim3(4, 8, 22), 256, 0, stream>>>(
        W_out, W_in, W_ip, b_ip, W_op, W_x, W_dt, WfT, Weq, Wcomb, WcT);

    // ---- layer 0 xz: x @ Weq + beq (fp32, K=32) ----
    xgemm0_k<<<dim3(BT / 64, 8, NBR), 256, 0, stream>>>(
        X0, X1, X2, X3, Weq, z_bf, xp_bf);

    for (int l = 0; l < NLAY; ++l) {
        if (l > 0) {
            bgemm_k<0><<<dim3(BT / 64, 4, NBR), 256, 0, stream>>>(
                yz_bf, (long)BT * DINNER, DINNER,
                WfT + (long)(l - 1) * 4 * 512 * DINNER, (long)512 * DINNER,
                xp_bf, (long)BT * DINNER,
                z_bf, (long)BT * DINNER,
                nullptr, 0, nullptr, 0);
        }
        // depthwise conv + silu (bf16 -> bf16), high-TLP
        conv_k<<<dim3((BT * DINNER) / (256 * 8), NBR), 256, 0, stream>>>(
            xp_bf, conv_w, conv_b, xc_bf, l);
        // dt = softplus(xc @ wc + b_dt) bf16; bc = xc @ wcBC f32  (N=384 padded)
        bgemm_k<3><<<dim3(BT / 64, 3, NBR), 256, 0, stream>>>(
            xc_bf, (long)BT * DINNER, DINNER,
            WcT + (long)l * NWB * DINNER, (long)NLAY * NWB * DINNER,
            dt_bf, (long)BT * DINNER,
            nullptr, 0,
            buf_bc, (long)BT * 32,
            b_dt + l * DINNER, (long)NLAY * DINNER);
        // chunked scan, s-split 512-thread blocks, LCH=64
        scan1_k<<<dim3(NCH - 1, Bk, NBR), 512, 0, stream>>>(
            dt_bf, xc_bf, buf_bc, A_log, recbuf, l);
        if (l < NLAY - 1) {
            scan3_k<0><<<dim3(NCH, Bk, NBR), 512, 0, stream>>>(
                dt_bf, xc_bf, buf_bc, z_bf, A_log, D_par, recbuf, yz_bf, nullptr, l);
        } else {
            scan3_k<1><<<dim3(NCH, Bk, NBR), 512, 0, stream>>>(
                dt_bf, xc_bf, buf_bc, z_bf, A_log, D_par, recbuf, yz_bf, part, l);
        }
    }

    // z_t = mean_t(yz) @ (Wout2 @ Wop) + bop
    csum2_k<<<16, 256, 0, stream>>>(part, Wcomb, b_op, out);
    final_k<<<1, 64, 0, stream>>>(out, out, eff);
}